// Round 2
// baseline (166.429 us; speedup 1.0000x reference)
//
#include <hip/hip_runtime.h>
#include <hip/hip_bf16.h>
#include <math.h>

#define N_NODES 8192
#define IN_FEAT 256
#define OUT_FEAT 128
#define WORDS_PER_ROW (N_NODES / 64)   // 128 u64 per row bitmap
#define CAP 512                         // max neighbors kept per row (E/N ~32, Poisson max ~70)
#define ROWS_PB 8

typedef unsigned long long u64;

__device__ __forceinline__ float wred_sum(float v) {
    #pragma unroll
    for (int o = 32; o > 0; o >>= 1) v += __shfl_down(v, o, 64);
    return v;   // valid in lane 0
}
__device__ __forceinline__ float wred_max(float v) {
    #pragma unroll
    for (int o = 32; o > 0; o >>= 1) v = fmaxf(v, __shfl_down(v, o, 64));
    return v;
}

// 8 rows per block, 128 threads. Computes hc rows (f32 to ws) and the four
// GAT score vectors csrc/cdst (from hc . ac_w halves), ssrc/sdst (from hs . as_w).
__global__ __launch_bounds__(128) void node_feats(
    const float* __restrict__ hctx, const float* __restrict__ hstr,
    const float* __restrict__ Wc,  const float* __restrict__ Wcb,
    const float* __restrict__ Ws,  const float* __restrict__ Wsb,
    const float* __restrict__ acw, const float* __restrict__ asw,
    float* __restrict__ hc,
    float* __restrict__ csrc, float* __restrict__ cdst,
    float* __restrict__ ssrc, float* __restrict__ sdst)
{
    __shared__ float ctx[ROWS_PB][IN_FEAT];
    __shared__ float strv[ROWS_PB][IN_FEAT];
    __shared__ float redA[2][ROWS_PB];        // row max
    __shared__ float redB[2][ROWS_PB];        // exp sum
    __shared__ float redD[2][ROWS_PB][4];     // 4 dots

    const int t  = threadIdx.x;
    const int wv = t >> 6, ln = t & 63;
    const int r0 = blockIdx.x * ROWS_PB;

    // cooperative vectorized load of 8 ctx rows + 8 structure rows
    {
        const float4* sc = (const float4*)(hctx + (size_t)r0 * IN_FEAT);
        const float4* ss = (const float4*)(hstr + (size_t)r0 * IN_FEAT);
        float4* dc4 = (float4*)&ctx[0][0];
        float4* ds4 = (float4*)&strv[0][0];
        #pragma unroll
        for (int k = 0; k < (ROWS_PB * IN_FEAT) / 4 / 128; k++) {
            dc4[t + k * 128] = sc[t + k * 128];
            ds4[t + k * 128] = ss[t + k * 128];
        }
    }
    __syncthreads();

    // per-row max of h_structure (thread owns elems t, t+128)
    #pragma unroll
    for (int r = 0; r < ROWS_PB; r++) {
        float m = wred_max(fmaxf(strv[r][t], strv[r][t + 128]));
        if (ln == 0) redA[wv][r] = m;
    }
    __syncthreads();

    // exp + per-row sum
    #pragma unroll
    for (int r = 0; r < ROWS_PB; r++) {
        float m = fmaxf(redA[0][r], redA[1][r]);
        float e0 = __expf(strv[r][t] - m);
        float e1 = __expf(strv[r][t + 128] - m);
        strv[r][t] = e0; strv[r][t + 128] = e1;   // owner-only slots
        float s = wred_sum(e0 + e1);
        if (ln == 0) redB[wv][r] = s;
    }
    __syncthreads();

    float inv[ROWS_PB];
    #pragma unroll
    for (int r = 0; r < ROWS_PB; r++) inv[r] = 1.0f / (redB[0][r] + redB[1][r]);

    // dual GEMV: thread t computes output dim t for all 8 rows
    const float4* wc4 = (const float4*)(Wc + (size_t)t * IN_FEAT);
    const float4* ws4 = (const float4*)(Ws + (size_t)t * IN_FEAT);
    float dc[ROWS_PB], dsv[ROWS_PB];
    #pragma unroll
    for (int r = 0; r < ROWS_PB; r++) { dc[r] = 0.0f; dsv[r] = 0.0f; }
    #pragma unroll 4
    for (int k4 = 0; k4 < IN_FEAT / 4; k4++) {
        float4 wcv = wc4[k4];
        float4 wsv = ws4[k4];
        int k = k4 * 4;
        #pragma unroll
        for (int r = 0; r < ROWS_PB; r++) {
            dc[r]  += ctx[r][k] * wcv.x + ctx[r][k+1] * wcv.y
                    + ctx[r][k+2] * wcv.z + ctx[r][k+3] * wcv.w;
            dsv[r] += strv[r][k] * wsv.x + strv[r][k+1] * wsv.y
                    + strv[r][k+2] * wsv.z + strv[r][k+3] * wsv.w;
        }
    }

    const float cb = Wcb[t], sb = Wsb[t];
    const float a0 = acw[t], a1 = acw[128 + t];
    const float b0 = asw[t], b1 = asw[128 + t];
    #pragma unroll
    for (int r = 0; r < ROWS_PB; r++) {
        float h_c = dc[r] + cb;
        float h_s = dsv[r] * inv[r] + sb;
        hc[(size_t)(r0 + r) * OUT_FEAT + t] = h_c;
        float v0 = wred_sum(h_c * a0);
        float v1 = wred_sum(h_c * a1);
        float v2 = wred_sum(h_s * b0);
        float v3 = wred_sum(h_s * b1);
        if (ln == 0) {
            redD[wv][r][0] = v0; redD[wv][r][1] = v1;
            redD[wv][r][2] = v2; redD[wv][r][3] = v3;
        }
    }
    __syncthreads();
    if (t < ROWS_PB * 4) {
        int r = t >> 2, q = t & 3;
        float v = redD[0][r][q] + redD[1][r][q];
        int node = r0 + r;
        if      (q == 0) csrc[node] = v;
        else if (q == 1) cdst[node] = v;
        else if (q == 2) ssrc[node] = v;
        else             sdst[node] = v;
    }
}

// Detect int64-vs-int32 edge_index layout: int64 data has zero high words at
// all odd int32 offsets; int32 data has random node indices there.
__global__ void detect_edge_fmt(const int* __restrict__ ei, int* __restrict__ flag)
{
    if (blockIdx.x == 0 && threadIdx.x == 0) {
        int orv = 0;
        for (int k = 1; k < 64; k += 2) orv |= ei[k];
        *flag = (orv == 0) ? 1 : 0;   // 1 => int64-as-int32-pairs
    }
}

__global__ __launch_bounds__(256) void scatter_edges(
    const int* __restrict__ ei, int E, const int* __restrict__ flag,
    u64* __restrict__ bmp)
{
    int e = blockIdx.x * blockDim.x + threadIdx.x;
    if (e >= E) return;
    int s, d;
    if (*flag) { s = ei[2 * e]; d = ei[2 * E + 2 * e]; }
    else       { s = ei[e];     d = ei[E + e]; }
    if ((unsigned)s < N_NODES && (unsigned)d < N_NODES)
        atomicOr(&bmp[(size_t)s * WORDS_PER_ROW + (d >> 6)], 1ull << (d & 63));
}

// One block (128 threads) per row i.
__global__ __launch_bounds__(128) void attn(
    const u64* __restrict__ bmp,
    const float* __restrict__ hc,
    const float* __restrict__ csrc, const float* __restrict__ cdst,
    const float* __restrict__ ssrc, const float* __restrict__ sdst,
    const float* __restrict__ wscoff, const float* __restrict__ wccoff,
    float* __restrict__ out)
{
    __shared__ int   jlist[CAP];
    __shared__ float plist[CAP];
    __shared__ float redM[2];
    __shared__ float redS[2];
    __shared__ int   cnt_sh;

    const int i = blockIdx.x;
    const int t = threadIdx.x;
    const int wv = t >> 6, ln = t & 63;
    if (t == 0) cnt_sh = 0;
    __syncthreads();

    const float wS = fabsf(wscoff[0]);   // scales alpha_c (per reference)
    const float wC = fabsf(wccoff[0]);   // scales alpha_s
    const float cs = csrc[i];
    const float ss = ssrc[i];

    // phase 1: bitmap scan; thread t owns j in [64t, 64t+64)
    u64 w = bmp[(size_t)i * WORDS_PER_ROW + t];
    while (w) {
        int b = __ffsll(w) - 1;
        w &= (w - 1);
        int j = t * 64 + b;
        float ac  = cs + cdst[j];
        float as_ = ss + sdst[j];
        ac  = (ac  > 0.0f) ? ac  : 0.01f * ac;
        as_ = (as_ > 0.0f) ? as_ : 0.01f * as_;
        float a = wS * ac + wC * as_;
        int idx = atomicAdd(&cnt_sh, 1);
        if (idx < CAP) { jlist[idx] = j; plist[idx] = a; }
    }
    __syncthreads();
    int cnt = cnt_sh; if (cnt > CAP) cnt = CAP;

    if (cnt == 0) {
        // all-NEG row -> uniform softmax -> column mean of hc
        float acc = 0.0f;
        for (int j = 0; j < N_NODES; j++) acc += hc[(size_t)j * OUT_FEAT + t];
        out[(size_t)i * OUT_FEAT + t] = acc / (float)N_NODES;
        return;
    }

    // phase 2: softmax over compacted list
    float lm = -1e30f;
    for (int k = t; k < cnt; k += 128) lm = fmaxf(lm, plist[k]);
    lm = wred_max(lm);
    if (ln == 0) redM[wv] = lm;
    __syncthreads();
    float m = fmaxf(redM[0], redM[1]);

    float ls = 0.0f;
    for (int k = t; k < cnt; k += 128) {
        float p = __expf(plist[k] - m);
        plist[k] = p;                     // owner-only slot
        ls += p;
    }
    ls = wred_sum(ls);
    if (ln == 0) redS[wv] = ls;
    __syncthreads();
    float inv = 1.0f / (redS[0] + redS[1]);

    // phase 3: weighted gather; thread t owns output dim t
    float acc = 0.0f;
    int k = 0;
    for (; k + 4 <= cnt; k += 4) {
        int   j0 = jlist[k],   j1 = jlist[k+1], j2 = jlist[k+2], j3 = jlist[k+3];
        float p0 = plist[k],   p1 = plist[k+1], p2 = plist[k+2], p3 = plist[k+3];
        acc += p0 * hc[(size_t)j0 * OUT_FEAT + t]
             + p1 * hc[(size_t)j1 * OUT_FEAT + t]
             + p2 * hc[(size_t)j2 * OUT_FEAT + t]
             + p3 * hc[(size_t)j3 * OUT_FEAT + t];
    }
    for (; k < cnt; k++) acc += plist[k] * hc[(size_t)jlist[k] * OUT_FEAT + t];

    out[(size_t)i * OUT_FEAT + t] = acc * inv;
}

extern "C" void kernel_launch(void* const* d_in, const int* in_sizes, int n_in,
                              void* d_out, int out_size, void* d_ws, size_t ws_size,
                              hipStream_t stream)
{
    const float* hctx = (const float*)d_in[0];
    const float* hstr = (const float*)d_in[1];
    const int*   ei   = (const int*)d_in[2];
    const float* Wc   = (const float*)d_in[3];
    const float* Wcb  = (const float*)d_in[4];
    const float* Ws   = (const float*)d_in[5];
    const float* Wsb  = (const float*)d_in[6];
    const float* acw  = (const float*)d_in[7];
    const float* asw  = (const float*)d_in[8];
    const float* wsco = (const float*)d_in[9];
    const float* wcco = (const float*)d_in[10];
    float* out = (float*)d_out;

    // E: in_sizes[2] is 2*E if int32 view (or int64-element view); 4*E if
    // int64 data surfaced as int32 count.
    const int n2 = in_sizes[2];
    const int E  = (n2 == 4 * 262144) ? 262144 : n2 / 2;

    // workspace layout
    char* ws = (char*)d_ws;
    size_t off = 0;
    float* hc   = (float*)(ws + off); off += (size_t)N_NODES * OUT_FEAT * sizeof(float);
    float* csrc = (float*)(ws + off); off += (size_t)N_NODES * sizeof(float);
    float* cdst = (float*)(ws + off); off += (size_t)N_NODES * sizeof(float);
    float* ssrc = (float*)(ws + off); off += (size_t)N_NODES * sizeof(float);
    float* sdst = (float*)(ws + off); off += (size_t)N_NODES * sizeof(float);
    off = (off + 255) & ~(size_t)255;
    u64* bmp    = (u64*)(ws + off);   off += (size_t)N_NODES * WORDS_PER_ROW * sizeof(u64);
    int* flag   = (int*)(ws + off);   off += 256;

    hipMemsetAsync(bmp, 0, (size_t)N_NODES * WORDS_PER_ROW * sizeof(u64), stream);

    detect_edge_fmt<<<1, 64, 0, stream>>>(ei, flag);
    node_feats<<<N_NODES / ROWS_PB, 128, 0, stream>>>(hctx, hstr, Wc, Wcb, Ws, Wsb,
                                                      acw, asw, hc, csrc, cdst, ssrc, sdst);
    scatter_edges<<<(E + 255) / 256, 256, 0, stream>>>(ei, E, flag, bmp);
    attn<<<N_NODES, 128, 0, stream>>>(bmp, hc, csrc, cdst, ssrc, sdst, wsco, wcco, out);
}

// Round 3
// 135.987 us; speedup vs baseline: 1.2239x; 1.2239x over previous
//
#include <hip/hip_runtime.h>
#include <hip/hip_bf16.h>
#include <math.h>

#define N_NODES 8192
#define IN_FEAT 256
#define OUT_FEAT 128
#define WORDS_PER_ROW (N_NODES / 64)
#define CAP 512
#define M_TILE 16

typedef unsigned long long u64;
typedef float v4f __attribute__((ext_vector_type(4)));
typedef short s8v __attribute__((ext_vector_type(8)));
typedef short s4v __attribute__((ext_vector_type(4)));

__device__ __forceinline__ float wred_sum_b(float v) {
    #pragma unroll
    for (int o = 32; o > 0; o >>= 1) v += __shfl_xor(v, o, 64);
    return v;   // all lanes
}
__device__ __forceinline__ float wred_max_b(float v) {
    #pragma unroll
    for (int o = 32; o > 0; o >>= 1) v = fmaxf(v, __shfl_xor(v, o, 64));
    return v;
}

// split f32 into bf16 hi (truncation) + bf16 lo (residual): ~16 mantissa bits
__device__ __forceinline__ void bsplit(float x, unsigned short& hi, unsigned short& lo) {
    unsigned int xb = __float_as_uint(x);
    hi = (unsigned short)(xb >> 16);
    float lof = x - __uint_as_float(xb & 0xFFFF0000u);
    lo = (unsigned short)(__float_as_uint(lof) >> 16);
}

// one-shot weight split: Wc, Ws (f32 [128][256]) -> bf16 hi/lo arrays
__global__ __launch_bounds__(256) void prep_w(
    const float* __restrict__ Wc, const float* __restrict__ Ws,
    unsigned short* __restrict__ wchi, unsigned short* __restrict__ wclo,
    unsigned short* __restrict__ wshi, unsigned short* __restrict__ wslo)
{
    int i = blockIdx.x * 256 + threadIdx.x;   // 0..32767
    unsigned short h, l;
    bsplit(Wc[i], h, l); wchi[i] = h; wclo[i] = l;
    bsplit(Ws[i], h, l); wshi[i] = h; wslo[i] = l;
}

// 512 blocks x 256 threads. M-tile = 16 rows. Wave w owns n in [32w, 32w+32).
// bf16-split MFMA for hc = ctx@Wc^T+b and hs = softmax(strv)@Ws^T+b, plus the
// four GAT score vectors.
__global__ __launch_bounds__(256) void node_feats(
    const float* __restrict__ hctx, const float* __restrict__ hstr,
    const unsigned short* __restrict__ wchi, const unsigned short* __restrict__ wclo,
    const unsigned short* __restrict__ wshi, const unsigned short* __restrict__ wslo,
    const float* __restrict__ Wcb, const float* __restrict__ Wsb,
    const float* __restrict__ acw, const float* __restrict__ asw,
    float* __restrict__ hc,
    float* __restrict__ csrc, float* __restrict__ cdst,
    float* __restrict__ ssrc, float* __restrict__ sdst)
{
    __shared__ unsigned short aCh[M_TILE][264], aCl[M_TILE][264];   // +8 pad: 2-way banks (free)
    __shared__ unsigned short aSh[M_TILE][264], aSl[M_TILE][264];
    __shared__ float invsh[M_TILE];
    __shared__ float hcT[M_TILE][132];
    __shared__ float hsT[M_TILE][132];

    const int t = threadIdx.x;
    const int w = t >> 6, ln = t & 63;
    const int r0 = blockIdx.x * M_TILE;

    // --- phase 1a: ctx -> bf16 hi/lo LDS (all 256 threads, coalesced float4) ---
    #pragma unroll
    for (int j = 0; j < 4; j++) {
        int c = t + 256 * j;          // chunk of 4 elems
        int r = c >> 6;
        int k = (c & 63) * 4;
        const float4 x = *(const float4*)(hctx + (size_t)(r0 + r) * IN_FEAT + k);
        unsigned short h0, h1, h2, h3, l0, l1, l2, l3;
        bsplit(x.x, h0, l0); bsplit(x.y, h1, l1);
        bsplit(x.z, h2, l2); bsplit(x.w, h3, l3);
        s4v hv = { (short)h0, (short)h1, (short)h2, (short)h3 };
        s4v lv = { (short)l0, (short)l1, (short)l2, (short)l3 };
        *(s4v*)&aCh[r][k] = hv;
        *(s4v*)&aCl[r][k] = lv;
    }

    // --- phase 1b: structure softmax (wave w owns rows 4w..4w+3), split to LDS ---
    #pragma unroll
    for (int rr = 0; rr < 4; rr++) {
        int r = w * 4 + rr;
        const float* srow = hstr + (size_t)(r0 + r) * IN_FEAT;
        float x0 = srow[ln], x1 = srow[ln + 64], x2 = srow[ln + 128], x3 = srow[ln + 192];
        float mx = wred_max_b(fmaxf(fmaxf(x0, x1), fmaxf(x2, x3)));
        float e0 = __expf(x0 - mx), e1 = __expf(x1 - mx);
        float e2 = __expf(x2 - mx), e3 = __expf(x3 - mx);
        float s = wred_sum_b(e0 + e1 + e2 + e3);
        if (ln == 0) invsh[r] = 1.0f / s;
        unsigned short h, l;
        bsplit(e0, h, l); aSh[r][ln]       = h; aSl[r][ln]       = l;
        bsplit(e1, h, l); aSh[r][ln + 64]  = h; aSl[r][ln + 64]  = l;
        bsplit(e2, h, l); aSh[r][ln + 128] = h; aSl[r][ln + 128] = l;
        bsplit(e3, h, l); aSh[r][ln + 192] = h; aSl[r][ln + 192] = l;
    }
    __syncthreads();

    // --- phase 2: MFMA K-loop ---
    const int m = ln & 15, q = ln >> 4;
    const int nA = (w << 5) + m, nB = nA + 16;
    const unsigned short* bchA = wchi + nA * IN_FEAT;
    const unsigned short* bchB = wchi + nB * IN_FEAT;
    const unsigned short* bclA = wclo + nA * IN_FEAT;
    const unsigned short* bclB = wclo + nB * IN_FEAT;
    const unsigned short* bshA = wshi + nA * IN_FEAT;
    const unsigned short* bshB = wshi + nB * IN_FEAT;
    const unsigned short* bslA = wslo + nA * IN_FEAT;
    const unsigned short* bslB = wslo + nB * IN_FEAT;

    v4f aC0 = {0.f,0.f,0.f,0.f}, aC1 = {0.f,0.f,0.f,0.f};
    v4f aS0 = {0.f,0.f,0.f,0.f}, aS1 = {0.f,0.f,0.f,0.f};

    #pragma unroll
    for (int ks = 0; ks < 8; ks++) {
        int ko = ks * 32 + q * 8;
        s8v ach = *(const s8v*)&aCh[m][ko];
        s8v acl = *(const s8v*)&aCl[m][ko];
        s8v ash = *(const s8v*)&aSh[m][ko];
        s8v asl = *(const s8v*)&aSl[m][ko];
        s8v bch0 = *(const s8v*)(bchA + ko);
        s8v bch1 = *(const s8v*)(bchB + ko);
        s8v bcl0 = *(const s8v*)(bclA + ko);
        s8v bcl1 = *(const s8v*)(bclB + ko);
        s8v bsh0 = *(const s8v*)(bshA + ko);
        s8v bsh1 = *(const s8v*)(bshB + ko);
        s8v bsl0 = *(const s8v*)(bslA + ko);
        s8v bsl1 = *(const s8v*)(bslB + ko);

        aC0 = __builtin_amdgcn_mfma_f32_16x16x32_bf16(acl, bch0, aC0, 0, 0, 0);
        aC0 = __builtin_amdgcn_mfma_f32_16x16x32_bf16(ach, bcl0, aC0, 0, 0, 0);
        aC0 = __builtin_amdgcn_mfma_f32_16x16x32_bf16(ach, bch0, aC0, 0, 0, 0);
        aC1 = __builtin_amdgcn_mfma_f32_16x16x32_bf16(acl, bch1, aC1, 0, 0, 0);
        aC1 = __builtin_amdgcn_mfma_f32_16x16x32_bf16(ach, bcl1, aC1, 0, 0, 0);
        aC1 = __builtin_amdgcn_mfma_f32_16x16x32_bf16(ach, bch1, aC1, 0, 0, 0);
        aS0 = __builtin_amdgcn_mfma_f32_16x16x32_bf16(asl, bsh0, aS0, 0, 0, 0);
        aS0 = __builtin_amdgcn_mfma_f32_16x16x32_bf16(ash, bsl0, aS0, 0, 0, 0);
        aS0 = __builtin_amdgcn_mfma_f32_16x16x32_bf16(ash, bsh0, aS0, 0, 0, 0);
        aS1 = __builtin_amdgcn_mfma_f32_16x16x32_bf16(asl, bsh1, aS1, 0, 0, 0);
        aS1 = __builtin_amdgcn_mfma_f32_16x16x32_bf16(ash, bsl1, aS1, 0, 0, 0);
        aS1 = __builtin_amdgcn_mfma_f32_16x16x32_bf16(ash, bsh1, aS1, 0, 0, 0);
    }

    // --- epilogue: C-layout (col=lane&15, row=quad*4+reg) -> LDS tiles ---
    const float cbA = Wcb[nA], cbB = Wcb[nB];
    const float sbA = Wsb[nA], sbB = Wsb[nB];
    #pragma unroll
    for (int p = 0; p < 4; p++) {
        int row = q * 4 + p;
        float iv = invsh[row];
        hcT[row][nA] = aC0[p] + cbA;
        hcT[row][nB] = aC1[p] + cbB;
        hsT[row][nA] = aS0[p] * iv + sbA;
        hsT[row][nB] = aS1[p] * iv + sbB;
    }
    __syncthreads();

    // hc tile -> global (coalesced)
    #pragma unroll
    for (int j = 0; j < 8; j++) {
        int f = t + 256 * j;
        int r = f >> 7, c = f & 127;
        hc[(size_t)(r0 + r) * OUT_FEAT + c] = hcT[r][c];
    }

    // four score dots per row; wave w handles rows {w, w+4, w+8, w+12}
    float a0 = acw[ln], a0b = acw[ln + 64], a1 = acw[128 + ln], a1b = acw[192 + ln];
    float b0 = asw[ln], b0b = asw[ln + 64], b1 = asw[128 + ln], b1b = asw[192 + ln];
    #pragma unroll
    for (int rr = 0; rr < 4; rr++) {
        int r = w + rr * 4;
        float c0 = hcT[r][ln], c1 = hcT[r][ln + 64];
        float s0 = hsT[r][ln], s1 = hsT[r][ln + 64];
        float v0 = wred_sum_b(c0 * a0 + c1 * a0b);
        float v1 = wred_sum_b(c0 * a1 + c1 * a1b);
        float v2 = wred_sum_b(s0 * b0 + s1 * b0b);
        float v3 = wred_sum_b(s0 * b1 + s1 * b1b);
        if (ln == 0) {
            csrc[r0 + r] = v0; cdst[r0 + r] = v1;
            ssrc[r0 + r] = v2; sdst[r0 + r] = v3;
        }
    }
}

// scatter with inline int64/int32 layout detection (32-lane ballot probe)
__global__ __launch_bounds__(256) void scatter_edges(
    const int* __restrict__ ei, int E, u64* __restrict__ bmp)
{
    __shared__ int is64sh;
    int pv = 0;
    if (threadIdx.x < 32) pv = ei[2 * threadIdx.x + 1];
    u64 nz = __ballot(pv != 0);
    if (threadIdx.x == 0) is64sh = (nz == 0) ? 1 : 0;
    __syncthreads();
    const int is64 = is64sh;

    int e = blockIdx.x * 256 + threadIdx.x;
    if (e >= E) return;
    int s, d;
    if (is64) { s = ei[2 * e]; d = ei[2 * E + 2 * e]; }
    else      { s = ei[e];     d = ei[E + e]; }
    if ((unsigned)s < N_NODES && (unsigned)d < N_NODES)
        atomicOr(&bmp[(size_t)s * WORDS_PER_ROW + (d >> 6)], 1ull << (d & 63));
}

// One block (128 threads) per row i.
__global__ __launch_bounds__(128) void attn(
    const u64* __restrict__ bmp,
    const float* __restrict__ hc,
    const float* __restrict__ csrc, const float* __restrict__ cdst,
    const float* __restrict__ ssrc, const float* __restrict__ sdst,
    const float* __restrict__ wscoff, const float* __restrict__ wccoff,
    float* __restrict__ out)
{
    __shared__ int   jlist[CAP];
    __shared__ float plist[CAP];
    __shared__ float redM[2];
    __shared__ float redS[2];
    __shared__ int   cnt_sh;

    const int i = blockIdx.x;
    const int t = threadIdx.x;
    const int wv = t >> 6, ln = t & 63;
    if (t == 0) cnt_sh = 0;
    __syncthreads();

    const float wS = fabsf(wscoff[0]);
    const float wC = fabsf(wccoff[0]);
    const float cs = csrc[i];
    const float ss = ssrc[i];

    u64 w = bmp[(size_t)i * WORDS_PER_ROW + t];
    while (w) {
        int b = __ffsll(w) - 1;
        w &= (w - 1);
        int j = t * 64 + b;
        float ac  = cs + cdst[j];
        float as_ = ss + sdst[j];
        ac  = (ac  > 0.0f) ? ac  : 0.01f * ac;
        as_ = (as_ > 0.0f) ? as_ : 0.01f * as_;
        float a = wS * ac + wC * as_;
        int idx = atomicAdd(&cnt_sh, 1);
        if (idx < CAP) { jlist[idx] = j; plist[idx] = a; }
    }
    __syncthreads();
    int cnt = cnt_sh; if (cnt > CAP) cnt = CAP;

    if (cnt == 0) {
        float acc = 0.0f;
        for (int j = 0; j < N_NODES; j++) acc += hc[(size_t)j * OUT_FEAT + t];
        out[(size_t)i * OUT_FEAT + t] = acc / (float)N_NODES;
        return;
    }

    float lm = -1e30f;
    for (int k = t; k < cnt; k += 128) lm = fmaxf(lm, plist[k]);
    lm = wred_max_b(lm);
    if (ln == 0) redM[wv] = lm;
    __syncthreads();
    float m = fmaxf(redM[0], redM[1]);

    float ls = 0.0f;
    for (int k = t; k < cnt; k += 128) {
        float p = __expf(plist[k] - m);
        plist[k] = p;
        ls += p;
    }
    ls = wred_sum_b(ls);
    if (ln == 0) redS[wv] = ls;
    __syncthreads();
    float inv = 1.0f / (redS[0] + redS[1]);

    float acc = 0.0f;
    int k = 0;
    for (; k + 4 <= cnt; k += 4) {
        int   j0 = jlist[k],   j1 = jlist[k+1], j2 = jlist[k+2], j3 = jlist[k+3];
        float p0 = plist[k],   p1 = plist[k+1], p2 = plist[k+2], p3 = plist[k+3];
        acc += p0 * hc[(size_t)j0 * OUT_FEAT + t]
             + p1 * hc[(size_t)j1 * OUT_FEAT + t]
             + p2 * hc[(size_t)j2 * OUT_FEAT + t]
             + p3 * hc[(size_t)j3 * OUT_FEAT + t];
    }
    for (; k < cnt; k++) acc += plist[k] * hc[(size_t)jlist[k] * OUT_FEAT + t];

    out[(size_t)i * OUT_FEAT + t] = acc * inv;
}

extern "C" void kernel_launch(void* const* d_in, const int* in_sizes, int n_in,
                              void* d_out, int out_size, void* d_ws, size_t ws_size,
                              hipStream_t stream)
{
    const float* hctx = (const float*)d_in[0];
    const float* hstr = (const float*)d_in[1];
    const int*   ei   = (const int*)d_in[2];
    const float* Wc   = (const float*)d_in[3];
    const float* Wcb  = (const float*)d_in[4];
    const float* Ws   = (const float*)d_in[5];
    const float* Wsb  = (const float*)d_in[6];
    const float* acw  = (const float*)d_in[7];
    const float* asw  = (const float*)d_in[8];
    const float* wsco = (const float*)d_in[9];
    const float* wcco = (const float*)d_in[10];
    float* out = (float*)d_out;

    const int n2 = in_sizes[2];
    const int E  = (n2 == 4 * 262144) ? 262144 : n2 / 2;

    char* ws = (char*)d_ws;
    size_t off = 0;
    float* hc   = (float*)(ws + off); off += (size_t)N_NODES * OUT_FEAT * sizeof(float);
    float* csrc = (float*)(ws + off); off += (size_t)N_NODES * sizeof(float);
    float* cdst = (float*)(ws + off); off += (size_t)N_NODES * sizeof(float);
    float* ssrc = (float*)(ws + off); off += (size_t)N_NODES * sizeof(float);
    float* sdst = (float*)(ws + off); off += (size_t)N_NODES * sizeof(float);
    off = (off + 255) & ~(size_t)255;
    u64* bmp    = (u64*)(ws + off);   off += (size_t)N_NODES * WORDS_PER_ROW * sizeof(u64);
    unsigned short* wchi = (unsigned short*)(ws + off); off += OUT_FEAT * IN_FEAT * sizeof(unsigned short);
    unsigned short* wclo = (unsigned short*)(ws + off); off += OUT_FEAT * IN_FEAT * sizeof(unsigned short);
    unsigned short* wshi = (unsigned short*)(ws + off); off += OUT_FEAT * IN_FEAT * sizeof(unsigned short);
    unsigned short* wslo = (unsigned short*)(ws + off); off += OUT_FEAT * IN_FEAT * sizeof(unsigned short);

    hipMemsetAsync(bmp, 0, (size_t)N_NODES * WORDS_PER_ROW * sizeof(u64), stream);

    prep_w<<<128, 256, 0, stream>>>(Wc, Ws, wchi, wclo, wshi, wslo);
    node_feats<<<N_NODES / M_TILE, 256, 0, stream>>>(hctx, hstr, wchi, wclo, wshi, wslo,
                                                     Wcb, Wsb, acw, asw,
                                                     hc, csrc, cdst, ssrc, sdst);
    scatter_edges<<<(E + 255) / 256, 256, 0, stream>>>(ei, E, bmp);
    attn<<<N_NODES, 128, 0, stream>>>(bmp, hc, csrc, cdst, ssrc, sdst, wsco, wcco, out);
}

// Round 4
// 130.329 us; speedup vs baseline: 1.2770x; 1.0434x over previous
//
#include <hip/hip_runtime.h>
#include <hip/hip_bf16.h>
#include <math.h>

#define N_NODES 8192
#define IN_FEAT 256
#define OUT_FEAT 128
#define WORDS_PER_ROW (N_NODES / 64)
#define CAPW 256
#define M_TILE 16

typedef unsigned long long u64;
typedef float v4f __attribute__((ext_vector_type(4)));
typedef short s8v __attribute__((ext_vector_type(8)));
typedef short s4v __attribute__((ext_vector_type(4)));

__device__ __forceinline__ float wred_sum_b(float v) {
    #pragma unroll
    for (int o = 32; o > 0; o >>= 1) v += __shfl_xor(v, o, 64);
    return v;   // all lanes
}
__device__ __forceinline__ float wred_max_b(float v) {
    #pragma unroll
    for (int o = 32; o > 0; o >>= 1) v = fmaxf(v, __shfl_xor(v, o, 64));
    return v;
}

// split f32 into bf16 hi (truncation) + bf16 lo (residual): ~16 mantissa bits
__device__ __forceinline__ void bsplit(float x, unsigned short& hi, unsigned short& lo) {
    unsigned int xb = __float_as_uint(x);
    hi = (unsigned short)(xb >> 16);
    float lof = x - __uint_as_float(xb & 0xFFFF0000u);
    lo = (unsigned short)(__float_as_uint(lof) >> 16);
}

__global__ __launch_bounds__(256) void prep_w(
    const float* __restrict__ Wc, const float* __restrict__ Ws,
    unsigned short* __restrict__ wchi, unsigned short* __restrict__ wclo,
    unsigned short* __restrict__ wshi, unsigned short* __restrict__ wslo)
{
    int i = blockIdx.x * 256 + threadIdx.x;
    unsigned short h, l;
    bsplit(Wc[i], h, l); wchi[i] = h; wclo[i] = l;
    bsplit(Ws[i], h, l); wshi[i] = h; wslo[i] = l;
}

// 512 blocks x 256 threads. Edge-scatter preamble (fire-and-forget atomics),
// then M-tile=16 bf16-split MFMA for hc/hs + the four GAT score vectors.
__global__ __launch_bounds__(256) void node_feats(
    const float* __restrict__ hctx, const float* __restrict__ hstr,
    const unsigned short* __restrict__ wchi, const unsigned short* __restrict__ wclo,
    const unsigned short* __restrict__ wshi, const unsigned short* __restrict__ wslo,
    const float* __restrict__ Wcb, const float* __restrict__ Wsb,
    const float* __restrict__ acw, const float* __restrict__ asw,
    const int* __restrict__ ei, int E, u64* __restrict__ bmp,
    float* __restrict__ hc,
    float* __restrict__ csrc, float* __restrict__ cdst,
    float* __restrict__ ssrc, float* __restrict__ sdst)
{
    __shared__ unsigned short aCh[M_TILE][264], aCl[M_TILE][264];   // +8 pad: 2-way banks (free)
    __shared__ unsigned short aSh[M_TILE][264], aSl[M_TILE][264];
    __shared__ float invsh[M_TILE];
    __shared__ float hcT[M_TILE][132];
    __shared__ float hsT[M_TILE][132];

    const int t = threadIdx.x;
    const int w = t >> 6, ln = t & 63;
    const int r0 = blockIdx.x * M_TILE;

    // --- phase 0: fused edge scatter (grid-stride; atomics need no wait) ---
    {
        // per-wave int64-layout probe: odd int32 words all zero => int64 pairs
        int pv = ei[2 * (ln & 31) + 1];
        u64 nz = __ballot(pv != 0);
        const int is64 = (nz == 0);
        for (int e = blockIdx.x * 256 + t; e < E; e += 512 * 256) {
            int s, d;
            if (is64) { s = ei[2 * e]; d = ei[2 * E + 2 * e]; }
            else      { s = ei[e];     d = ei[E + e]; }
            if ((unsigned)s < N_NODES && (unsigned)d < N_NODES)
                atomicOr(&bmp[(size_t)s * WORDS_PER_ROW + (d >> 6)], 1ull << (d & 63));
        }
    }

    // --- phase 1a: ctx -> bf16 hi/lo LDS ---
    #pragma unroll
    for (int j = 0; j < 4; j++) {
        int c = t + 256 * j;
        int r = c >> 6;
        int k = (c & 63) * 4;
        const float4 x = *(const float4*)(hctx + (size_t)(r0 + r) * IN_FEAT + k);
        unsigned short h0, h1, h2, h3, l0, l1, l2, l3;
        bsplit(x.x, h0, l0); bsplit(x.y, h1, l1);
        bsplit(x.z, h2, l2); bsplit(x.w, h3, l3);
        s4v hv = { (short)h0, (short)h1, (short)h2, (short)h3 };
        s4v lv = { (short)l0, (short)l1, (short)l2, (short)l3 };
        *(s4v*)&aCh[r][k] = hv;
        *(s4v*)&aCl[r][k] = lv;
    }

    // --- phase 1b: structure softmax (wave w owns rows 4w..4w+3) ---
    #pragma unroll
    for (int rr = 0; rr < 4; rr++) {
        int r = w * 4 + rr;
        const float* srow = hstr + (size_t)(r0 + r) * IN_FEAT;
        float x0 = srow[ln], x1 = srow[ln + 64], x2 = srow[ln + 128], x3 = srow[ln + 192];
        float mx = wred_max_b(fmaxf(fmaxf(x0, x1), fmaxf(x2, x3)));
        float e0 = __expf(x0 - mx), e1 = __expf(x1 - mx);
        float e2 = __expf(x2 - mx), e3 = __expf(x3 - mx);
        float s = wred_sum_b(e0 + e1 + e2 + e3);
        if (ln == 0) invsh[r] = 1.0f / s;
        unsigned short h, l;
        bsplit(e0, h, l); aSh[r][ln]       = h; aSl[r][ln]       = l;
        bsplit(e1, h, l); aSh[r][ln + 64]  = h; aSl[r][ln + 64]  = l;
        bsplit(e2, h, l); aSh[r][ln + 128] = h; aSl[r][ln + 128] = l;
        bsplit(e3, h, l); aSh[r][ln + 192] = h; aSl[r][ln + 192] = l;
    }
    __syncthreads();

    // --- phase 2: MFMA K-loop ---
    const int m = ln & 15, q = ln >> 4;
    const int nA = (w << 5) + m, nB = nA + 16;
    const unsigned short* bchA = wchi + nA * IN_FEAT;
    const unsigned short* bchB = wchi + nB * IN_FEAT;
    const unsigned short* bclA = wclo + nA * IN_FEAT;
    const unsigned short* bclB = wclo + nB * IN_FEAT;
    const unsigned short* bshA = wshi + nA * IN_FEAT;
    const unsigned short* bshB = wshi + nB * IN_FEAT;
    const unsigned short* bslA = wslo + nA * IN_FEAT;
    const unsigned short* bslB = wslo + nB * IN_FEAT;

    v4f aC0 = {0.f,0.f,0.f,0.f}, aC1 = {0.f,0.f,0.f,0.f};
    v4f aS0 = {0.f,0.f,0.f,0.f}, aS1 = {0.f,0.f,0.f,0.f};

    #pragma unroll
    for (int ks = 0; ks < 8; ks++) {
        int ko = ks * 32 + q * 8;
        s8v ach = *(const s8v*)&aCh[m][ko];
        s8v acl = *(const s8v*)&aCl[m][ko];
        s8v ash = *(const s8v*)&aSh[m][ko];
        s8v asl = *(const s8v*)&aSl[m][ko];
        s8v bch0 = *(const s8v*)(bchA + ko);
        s8v bch1 = *(const s8v*)(bchB + ko);
        s8v bcl0 = *(const s8v*)(bclA + ko);
        s8v bcl1 = *(const s8v*)(bclB + ko);
        s8v bsh0 = *(const s8v*)(bshA + ko);
        s8v bsh1 = *(const s8v*)(bshB + ko);
        s8v bsl0 = *(const s8v*)(bslA + ko);
        s8v bsl1 = *(const s8v*)(bslB + ko);

        aC0 = __builtin_amdgcn_mfma_f32_16x16x32_bf16(acl, bch0, aC0, 0, 0, 0);
        aC0 = __builtin_amdgcn_mfma_f32_16x16x32_bf16(ach, bcl0, aC0, 0, 0, 0);
        aC0 = __builtin_amdgcn_mfma_f32_16x16x32_bf16(ach, bch0, aC0, 0, 0, 0);
        aC1 = __builtin_amdgcn_mfma_f32_16x16x32_bf16(acl, bch1, aC1, 0, 0, 0);
        aC1 = __builtin_amdgcn_mfma_f32_16x16x32_bf16(ach, bcl1, aC1, 0, 0, 0);
        aC1 = __builtin_amdgcn_mfma_f32_16x16x32_bf16(ach, bch1, aC1, 0, 0, 0);
        aS0 = __builtin_amdgcn_mfma_f32_16x16x32_bf16(asl, bsh0, aS0, 0, 0, 0);
        aS0 = __builtin_amdgcn_mfma_f32_16x16x32_bf16(ash, bsl0, aS0, 0, 0, 0);
        aS0 = __builtin_amdgcn_mfma_f32_16x16x32_bf16(ash, bsh0, aS0, 0, 0, 0);
        aS1 = __builtin_amdgcn_mfma_f32_16x16x32_bf16(asl, bsh1, aS1, 0, 0, 0);
        aS1 = __builtin_amdgcn_mfma_f32_16x16x32_bf16(ash, bsl1, aS1, 0, 0, 0);
        aS1 = __builtin_amdgcn_mfma_f32_16x16x32_bf16(ash, bsh1, aS1, 0, 0, 0);
    }

    // --- epilogue: C-layout (col=lane&15, row=quad*4+reg) -> LDS tiles ---
    const float cbA = Wcb[nA], cbB = Wcb[nB];
    const float sbA = Wsb[nA], sbB = Wsb[nB];
    #pragma unroll
    for (int p = 0; p < 4; p++) {
        int row = q * 4 + p;
        float iv = invsh[row];
        hcT[row][nA] = aC0[p] + cbA;
        hcT[row][nB] = aC1[p] + cbB;
        hsT[row][nA] = aS0[p] * iv + sbA;
        hsT[row][nB] = aS1[p] * iv + sbB;
    }
    __syncthreads();

    #pragma unroll
    for (int j = 0; j < 8; j++) {
        int f = t + 256 * j;
        int r = f >> 7, c = f & 127;
        hc[(size_t)(r0 + r) * OUT_FEAT + c] = hcT[r][c];
    }

    float a0 = acw[ln], a0b = acw[ln + 64], a1 = acw[128 + ln], a1b = acw[192 + ln];
    float b0 = asw[ln], b0b = asw[ln + 64], b1 = asw[128 + ln], b1b = asw[192 + ln];
    #pragma unroll
    for (int rr = 0; rr < 4; rr++) {
        int r = w + rr * 4;
        float c0 = hcT[r][ln], c1 = hcT[r][ln + 64];
        float s0 = hsT[r][ln], s1 = hsT[r][ln + 64];
        float v0 = wred_sum_b(c0 * a0 + c1 * a0b);
        float v1 = wred_sum_b(c0 * a1 + c1 * a1b);
        float v2 = wred_sum_b(s0 * b0 + s1 * b0b);
        float v3 = wred_sum_b(s0 * b1 + s1 * b1b);
        if (ln == 0) {
            csrc[r0 + r] = v0; cdst[r0 + r] = v1;
            ssrc[r0 + r] = v2; sdst[r0 + r] = v3;
        }
    }
}

// One WAVE per row: 2048 blocks x 256 threads (4 rows/block). No block barriers.
__global__ __launch_bounds__(256) void attn(
    const u64* __restrict__ bmp,
    const float* __restrict__ hc,
    const float* __restrict__ csrc, const float* __restrict__ cdst,
    const float* __restrict__ ssrc, const float* __restrict__ sdst,
    const float* __restrict__ wscoff, const float* __restrict__ wccoff,
    float* __restrict__ out)
{
    __shared__ int   jl[4][CAPW];
    __shared__ float pl[4][CAPW];

    const int w  = threadIdx.x >> 6;
    const int ln = threadIdx.x & 63;
    const int i  = blockIdx.x * 4 + w;

    const float wS = fabsf(wscoff[0]);
    const float wC = fabsf(wccoff[0]);
    const float cs = csrc[i], ss = ssrc[i];

    // lane owns bitmap words 2ln, 2ln+1 (16 B coalesced)
    ulonglong2 wv = *(const ulonglong2*)(bmp + (size_t)i * WORDS_PER_ROW + 2 * ln);
    int c = __popcll(wv.x) + __popcll(wv.y);

    // exclusive prefix scan over 64 lanes
    int inc = c;
    #pragma unroll
    for (int o = 1; o < 64; o <<= 1) {
        int y = __shfl_up(inc, o, 64);
        if (ln >= o) inc += y;
    }
    int pre = inc - c;
    int cnt = __shfl(inc, 63, 64);

    // compact (j, alpha) into LDS
    int idx = pre;
    #pragma unroll
    for (int h = 0; h < 2; h++) {
        u64 ww = (h == 0) ? wv.x : wv.y;
        int jb = ln * 128 + h * 64;
        while (ww) {
            int b = __ffsll(ww) - 1; ww &= ww - 1;
            int j = jb + b;
            float ac  = cs + cdst[j];
            float as_ = ss + sdst[j];
            ac  = (ac  > 0.0f) ? ac  : 0.01f * ac;
            as_ = (as_ > 0.0f) ? as_ : 0.01f * as_;
            if (idx < CAPW) { jl[w][idx] = j; pl[w][idx] = wS * ac + wC * as_; }
            idx++;
        }
    }
    if (cnt > CAPW) cnt = CAPW;
    __threadfence_block();   // drain lgkm; wave-synchronous visibility

    if (cnt == 0) {
        // all-NEG row -> uniform softmax -> column mean of hc (never in practice)
        float2 acc = {0.f, 0.f};
        const float2* hc2 = (const float2*)hc;
        for (int j = 0; j < N_NODES; j++) {
            float2 h2 = hc2[(size_t)j * 64 + ln];
            acc.x += h2.x; acc.y += h2.y;
        }
        float2 o2 = { acc.x / (float)N_NODES, acc.y / (float)N_NODES };
        *(float2*)(out + (size_t)i * OUT_FEAT + 2 * ln) = o2;
        return;
    }

    // wave softmax over compacted list
    float m = -1e30f;
    for (int k = ln; k < cnt; k += 64) m = fmaxf(m, pl[w][k]);
    m = wred_max_b(m);
    float s = 0.0f;
    for (int k = ln; k < cnt; k += 64) {
        float p = __expf(pl[w][k] - m);
        pl[w][k] = p;
        s += p;
    }
    s = wred_sum_b(s);
    float inv = 1.0f / s;
    __threadfence_block();

    // gather: lane owns dims 2ln, 2ln+1
    const float2* hc2 = (const float2*)hc;
    float2 acc = {0.f, 0.f};
    int k = 0;
    for (; k + 4 <= cnt; k += 4) {
        int   j0 = jl[w][k],   j1 = jl[w][k+1], j2 = jl[w][k+2], j3 = jl[w][k+3];
        float p0 = pl[w][k],   p1 = pl[w][k+1], p2 = pl[w][k+2], p3 = pl[w][k+3];
        float2 h0 = hc2[(size_t)j0 * 64 + ln];
        float2 h1 = hc2[(size_t)j1 * 64 + ln];
        float2 h2 = hc2[(size_t)j2 * 64 + ln];
        float2 h3 = hc2[(size_t)j3 * 64 + ln];
        acc.x += p0 * h0.x + p1 * h1.x + p2 * h2.x + p3 * h3.x;
        acc.y += p0 * h0.y + p1 * h1.y + p2 * h2.y + p3 * h3.y;
    }
    for (; k < cnt; k++) {
        float2 h0 = hc2[(size_t)jl[w][k] * 64 + ln];
        float p0 = pl[w][k];
        acc.x += p0 * h0.x; acc.y += p0 * h0.y;
    }
    float2 o2 = { acc.x * inv, acc.y * inv };
    *(float2*)(out + (size_t)i * OUT_FEAT + 2 * ln) = o2;
}

extern "C" void kernel_launch(void* const* d_in, const int* in_sizes, int n_in,
                              void* d_out, int out_size, void* d_ws, size_t ws_size,
                              hipStream_t stream)
{
    const float* hctx = (const float*)d_in[0];
    const float* hstr = (const float*)d_in[1];
    const int*   ei   = (const int*)d_in[2];
    const float* Wc   = (const float*)d_in[3];
    const float* Wcb  = (const float*)d_in[4];
    const float* Ws   = (const float*)d_in[5];
    const float* Wsb  = (const float*)d_in[6];
    const float* acw  = (const float*)d_in[7];
    const float* asw  = (const float*)d_in[8];
    const float* wsco = (const float*)d_in[9];
    const float* wcco = (const float*)d_in[10];
    float* out = (float*)d_out;

    const int n2 = in_sizes[2];
    const int E  = (n2 == 4 * 262144) ? 262144 : n2 / 2;

    char* ws = (char*)d_ws;
    size_t off = 0;
    float* hc   = (float*)(ws + off); off += (size_t)N_NODES * OUT_FEAT * sizeof(float);
    float* csrc = (float*)(ws + off); off += (size_t)N_NODES * sizeof(float);
    float* cdst = (float*)(ws + off); off += (size_t)N_NODES * sizeof(float);
    float* ssrc = (float*)(ws + off); off += (size_t)N_NODES * sizeof(float);
    float* sdst = (float*)(ws + off); off += (size_t)N_NODES * sizeof(float);
    off = (off + 255) & ~(size_t)255;
    u64* bmp    = (u64*)(ws + off);   off += (size_t)N_NODES * WORDS_PER_ROW * sizeof(u64);
    unsigned short* wchi = (unsigned short*)(ws + off); off += OUT_FEAT * IN_FEAT * sizeof(unsigned short);
    unsigned short* wclo = (unsigned short*)(ws + off); off += OUT_FEAT * IN_FEAT * sizeof(unsigned short);
    unsigned short* wshi = (unsigned short*)(ws + off); off += OUT_FEAT * IN_FEAT * sizeof(unsigned short);
    unsigned short* wslo = (unsigned short*)(ws + off); off += OUT_FEAT * IN_FEAT * sizeof(unsigned short);

    hipMemsetAsync(bmp, 0, (size_t)N_NODES * WORDS_PER_ROW * sizeof(u64), stream);

    prep_w<<<128, 256, 0, stream>>>(Wc, Ws, wchi, wclo, wshi, wslo);
    node_feats<<<N_NODES / M_TILE, 256, 0, stream>>>(hctx, hstr, wchi, wclo, wshi, wslo,
                                                     Wcb, Wsb, acw, asw, ei, E, bmp,
                                                     hc, csrc, cdst, ssrc, sdst);
    attn<<<N_NODES / 4, 256, 0, stream>>>(bmp, hc, csrc, cdst, ssrc, sdst, wsco, wcco, out);
}